// Round 5
// baseline (479.603 us; speedup 1.0000x reference)
//
#include <hip/hip_runtime.h>
#include <hip/hip_cooperative_groups.h>

namespace cg = cooperative_groups;

// B=8, C=64, H=256, W=512, 3x3 spherical taps, O=1, 2x2 upsample -> (8,1,512,1024) fp32.
#define Bn   8
#define Cn   64
#define Hn   256
#define Wn   512
#define HWn  (Hn * Wn)
#define TAPS 9
#define BH   4            // batches per D slot (layout: D[k*2+half][p][b4])

typedef float vfloat2 __attribute__((ext_vector_type(2)));  // NT-store-compatible

// ---------------------------------------------------------------------------
// Fused kernel (cooperative): phase A = round-1 pass1 (NT loads restored,
// best measured config), grid.sync(), phase B = round-1 pass2.
// Grid 512 x 256: phase A does both batch-halves per strip sequentially,
// phase B does one strip. Co-residency: 2 blocks/CU, 9.2 KB LDS, VGPR<<256.
// Purpose: (a) one less launch, (b) the fused dispatch aggregates
// pass1+pass2 time -> if it exceeds the ~160 us fills it surfaces in the
// top-5 rocprof rows with its own FETCH/WRITE for direct attribution.
// ---------------------------------------------------------------------------
__global__ __launch_bounds__(256, 2) void fused_kernel(
    const float* __restrict__ feat, const float* __restrict__ wt,
    const int* __restrict__ gi, const int* __restrict__ gj,
    float* __restrict__ D, float* __restrict__ out)
{
    const int tid = threadIdx.x;
    const int blk = blockIdx.x;              // 0..511 strips
    const int p   = blk * 256 + tid;

    // ---------------- Phase A: channel-dot ----------------
    for (int half = 0; half < 2; ++half) {   // runtime trip-2 loop; all array
        const float* fbase = feat + (size_t)half * BH * Cn * HWn + p;

        float acc[TAPS][BH];                 //  indices below are compile-time
#pragma unroll
        for (int k = 0; k < TAPS; ++k)
#pragma unroll
            for (int b = 0; b < BH; ++b) acc[k][b] = 0.f;

        float buf[2][4][BH];

        // prologue: chunk 0 (c = 0..3), nontemporal (evict-first) loads
#pragma unroll
        for (int ci = 0; ci < 4; ++ci)
#pragma unroll
            for (int b = 0; b < BH; ++b)
                buf[0][ci][b] = __builtin_nontemporal_load(
                    fbase + (size_t)(b * Cn + ci) * HWn);

#pragma unroll
        for (int g = 0; g < 16; ++g) {
            const int cur = g & 1, nxt = cur ^ 1;
            if (g < 15) {                    // prefetch chunk g+1
                const int c0 = (g + 1) * 4;
#pragma unroll
                for (int ci = 0; ci < 4; ++ci)
#pragma unroll
                    for (int b = 0; b < BH; ++b)
                        buf[nxt][ci][b] = __builtin_nontemporal_load(
                            fbase + (size_t)(b * Cn + c0 + ci) * HWn);
            }
#pragma unroll
            for (int ci = 0; ci < 4; ++ci) {
                const int c = g * 4 + ci;
#pragma unroll
                for (int k = 0; k < TAPS; ++k) {
                    const float wv = wt[c * TAPS + k];   // uniform -> SGPR
#pragma unroll
                    for (int b = 0; b < BH; ++b)
                        acc[k][b] = fmaf(buf[cur][ci][b], wv, acc[k][b]);
                }
            }
        }

        // store: one float4 per tap, lanes contiguous -> fully coalesced
#pragma unroll
        for (int k = 0; k < TAPS; ++k) {
            float4* dst = (float4*)(D + ((size_t)(k * 2 + half) * HWn + p) * BH);
            *dst = make_float4(acc[k][0], acc[k][1], acc[k][2], acc[k][3]);
        }
    }

    cg::this_grid().sync();                  // all D written before any gather

    // ---------------- Phase B: gather + 2x2 upsample ----------------
    __shared__ int loff[256 * TAPS];
    const int p0    = blk * 256;
    const int gbase = p0 * TAPS;

#pragma unroll
    for (int i = tid; i < 256 * TAPS; i += 256)
        loff[i] = gi[gbase + i] * Wn + gj[gbase + i];
    __syncthreads();

    const int w = p & (Wn - 1);
    const int h = p >> 9;

    int off[TAPS];
#pragma unroll
    for (int k = 0; k < TAPS; ++k) off[k] = loff[tid * TAPS + k];

    float4 x0[TAPS], x1[TAPS];
#pragma unroll
    for (int k = 0; k < TAPS; ++k) {
        x0[k] = *(const float4*)(D + ((size_t)(2 * k)     * HWn + off[k]) * BH);
        x1[k] = *(const float4*)(D + ((size_t)(2 * k + 1) * HWn + off[k]) * BH);
    }

    float a[Bn];
#pragma unroll
    for (int b = 0; b < Bn; ++b) a[b] = 0.f;
#pragma unroll
    for (int k = 0; k < TAPS; ++k) {
        a[0] += x0[k].x; a[1] += x0[k].y; a[2] += x0[k].z; a[3] += x0[k].w;
        a[4] += x1[k].x; a[5] += x1[k].y; a[6] += x1[k].z; a[7] += x1[k].w;
    }

#pragma unroll
    for (int b = 0; b < Bn; ++b) {
        vfloat2 vv = {a[b], a[b]};
        size_t o = ((size_t)b * (2 * Hn) + 2 * h) * (size_t)(2 * Wn) + 2 * w;
        __builtin_nontemporal_store(vv, (vfloat2*)(out + o));
        __builtin_nontemporal_store(vv, (vfloat2*)(out + o + 2 * Wn));
    }
}

// ---------------------------------------------------------------------------
// Fallback path 1 (cooperative enqueue rejected): round-1 two-kernel pipeline.
// ---------------------------------------------------------------------------
__global__ __launch_bounds__(256, 4) void pass1_chandot(
    const float* __restrict__ feat, const float* __restrict__ wt,
    float* __restrict__ D)
{
    const int strip = blockIdx.x & 511;
    const int half  = blockIdx.x >> 9;
    const int p     = strip * 256 + (int)threadIdx.x;
    const float* fbase = feat + (size_t)half * BH * Cn * HWn + p;

    float acc[TAPS][BH];
#pragma unroll
    for (int k = 0; k < TAPS; ++k)
#pragma unroll
        for (int b = 0; b < BH; ++b) acc[k][b] = 0.f;

    float buf[2][4][BH];
#pragma unroll
    for (int ci = 0; ci < 4; ++ci)
#pragma unroll
        for (int b = 0; b < BH; ++b)
            buf[0][ci][b] = __builtin_nontemporal_load(
                fbase + (size_t)(b * Cn + ci) * HWn);

#pragma unroll
    for (int g = 0; g < 16; ++g) {
        const int cur = g & 1, nxt = cur ^ 1;
        if (g < 15) {
            const int c0 = (g + 1) * 4;
#pragma unroll
            for (int ci = 0; ci < 4; ++ci)
#pragma unroll
                for (int b = 0; b < BH; ++b)
                    buf[nxt][ci][b] = __builtin_nontemporal_load(
                        fbase + (size_t)(b * Cn + c0 + ci) * HWn);
        }
#pragma unroll
        for (int ci = 0; ci < 4; ++ci) {
            const int c = g * 4 + ci;
#pragma unroll
            for (int k = 0; k < TAPS; ++k) {
                const float wv = wt[c * TAPS + k];
#pragma unroll
                for (int b = 0; b < BH; ++b)
                    acc[k][b] = fmaf(buf[cur][ci][b], wv, acc[k][b]);
            }
        }
    }

#pragma unroll
    for (int k = 0; k < TAPS; ++k) {
        float4* dst = (float4*)(D + ((size_t)(k * 2 + half) * HWn + p) * BH);
        *dst = make_float4(acc[k][0], acc[k][1], acc[k][2], acc[k][3]);
    }
}

__global__ __launch_bounds__(256) void pass2_gather(
    const float* __restrict__ D, const int* __restrict__ gi,
    const int* __restrict__ gj, float* __restrict__ out)
{
    __shared__ int loff[256 * TAPS];
    const int tid   = threadIdx.x;
    const int p0    = blockIdx.x * 256;
    const int gbase = p0 * TAPS;

#pragma unroll
    for (int i = tid; i < 256 * TAPS; i += 256)
        loff[i] = gi[gbase + i] * Wn + gj[gbase + i];
    __syncthreads();

    const int p = p0 + tid;
    const int w = p & (Wn - 1);
    const int h = p >> 9;

    int off[TAPS];
#pragma unroll
    for (int k = 0; k < TAPS; ++k) off[k] = loff[tid * TAPS + k];

    float4 x0[TAPS], x1[TAPS];
#pragma unroll
    for (int k = 0; k < TAPS; ++k) {
        x0[k] = *(const float4*)(D + ((size_t)(2 * k)     * HWn + off[k]) * BH);
        x1[k] = *(const float4*)(D + ((size_t)(2 * k + 1) * HWn + off[k]) * BH);
    }

    float a[Bn];
#pragma unroll
    for (int b = 0; b < Bn; ++b) a[b] = 0.f;
#pragma unroll
    for (int k = 0; k < TAPS; ++k) {
        a[0] += x0[k].x; a[1] += x0[k].y; a[2] += x0[k].z; a[3] += x0[k].w;
        a[4] += x1[k].x; a[5] += x1[k].y; a[6] += x1[k].z; a[7] += x1[k].w;
    }

#pragma unroll
    for (int b = 0; b < Bn; ++b) {
        vfloat2 vv = {a[b], a[b]};
        size_t o = ((size_t)b * (2 * Hn) + 2 * h) * (size_t)(2 * Wn) + 2 * w;
        __builtin_nontemporal_store(vv, (vfloat2*)(out + o));
        __builtin_nontemporal_store(vv, (vfloat2*)(out + o + 2 * Wn));
    }
}

// ---------------------------------------------------------------------------
// Fallback path 2 (ws too small): direct per-pixel 9x64 gather-dot.
// ---------------------------------------------------------------------------
__global__ __launch_bounds__(256) void direct_kernel(
    const float* __restrict__ feat, const float* __restrict__ wt,
    const int* __restrict__ gi, const int* __restrict__ gj,
    float* __restrict__ out)
{
    int p = blockIdx.x * blockDim.x + threadIdx.x;
    int w = p & (Wn - 1);
    int h = (p >> 9) & (Hn - 1);
    int b = p >> 17;

    int iidx = ((h << 9) | w) * TAPS;
    int off[TAPS];
#pragma unroll
    for (int k = 0; k < TAPS; ++k)
        off[k] = gi[iidx + k] * Wn + gj[iidx + k];

    float acc = 0.f;
    for (int c = 0; c < Cn; ++c) {
        const float* fc = feat + ((size_t)b * Cn + c) * HWn;
#pragma unroll
        for (int k = 0; k < TAPS; ++k)
            acc = fmaf(fc[off[k]], wt[c * TAPS + k], acc);
    }

    float2 v = make_float2(acc, acc);
    size_t o0 = ((size_t)b * (2 * Hn) + 2 * h) * (size_t)(2 * Wn) + 2 * w;
    *(float2*)(out + o0)          = v;
    *(float2*)(out + o0 + 2 * Wn) = v;
}

extern "C" void kernel_launch(void* const* d_in, const int* in_sizes, int n_in,
                              void* d_out, int out_size, void* d_ws, size_t ws_size,
                              hipStream_t stream) {
    const float* feat = (const float*)d_in[0];   // [8,64,256,512] fp32
    const float* wt   = (const float*)d_in[1];   // [1,64,3,3]     fp32
    const int*   gi   = (const int*)d_in[2];     // [256,512,9]    int32
    const int*   gj   = (const int*)d_in[3];     // [256,512,9]    int32
    float*       out  = (float*)d_out;           // [8,1,512,1024] fp32

    // D[k*2+half][p][b4]
    const size_t bytesD = (size_t)TAPS * 2 * HWn * BH * sizeof(float); // 37.75 MB

    if (ws_size >= bytesD) {
        float* D = (float*)d_ws;
        void* args[] = {(void*)&feat, (void*)&wt, (void*)&gi, (void*)&gj,
                        (void*)&D, (void*)&out};
        hipError_t e = hipLaunchCooperativeKernel(
            (const void*)fused_kernel, dim3(HWn / 256), dim3(256), args, 0, stream);
        if (e != hipSuccess) {
            // cooperative enqueue rejected (e.g. under capture) -> r1 pipeline
            pass1_chandot<<<2 * (HWn / 256), 256, 0, stream>>>(feat, wt, D);
            pass2_gather <<<HWn / 256, 256, 0, stream>>>(D, gi, gj, out);
        }
    } else {
        direct_kernel<<<(Bn * HWn) / 256, 256, 0, stream>>>(feat, wt, gi, gj, out);
    }
}

// Round 7
// 364.066 us; speedup vs baseline: 1.3173x; 1.3173x over previous
//
#include <hip/hip_runtime.h>

// B=8, C=64, H=256, W=512, 3x3 spherical taps, O=1, 2x2 upsample -> (8,1,512,1024) fp32.
// ---------------------------------------------------------------------------
// ROUND-1 CONFIGURATION RESTORED (best measured: 365.06 us).
// Session decomposition (r0-r5 evidence):
//   dur_us ~= 161 (harness 1-GiB ws-poison fill, 6.6 TB/s, fixed)
//           + ~148 (harness restore/launch gaps, fixed)
//           +  ~56 (pass1+pass2, vs ~46-50 us mandatory-traffic floor)
// Measured null/negative levers: load width x4 (null), occupancy 8->16
// waves/CU (null), plain vs NT loads (NT better by ~20 us: L3 pollution),
// D-store scatter (+13.5 us), cooperative fusion (+114 us: halved phase-A
// parallelism + grid.sync). Kernels are ~90% of their BW roofline.
// ---------------------------------------------------------------------------
#define Bn   8
#define Cn   64
#define Hn   256
#define Wn   512
#define HWn  (Hn * Wn)
#define TAPS 9
#define BH   4            // batches per thread in pass1 (batch-split halves)

typedef float vfloat2 __attribute__((ext_vector_type(2)));  // NT-store-compatible

// ---------------------------------------------------------------------------
// Pass 1: channel-dot, batch-split.
//   D[k*2+half][p][b4] = sum_c feat[half*4+b4][c][p] * wt[c][k]
// Thread = one pixel x 4 batches. Double-buffered chunks of 4 channels,
// NT (evict-first) loads keep the 268 MB feature stream from evicting D
// out of L2/L3. 16 waves/CU. Weights are wave-uniform -> scalar reads.
// ---------------------------------------------------------------------------
__global__ __launch_bounds__(256, 4) void pass1_chandot(
    const float* __restrict__ feat, const float* __restrict__ wt,
    float* __restrict__ D)
{
    const int strip = blockIdx.x & 511;              // 512 strips of 256 px
    const int half  = blockIdx.x >> 9;               // batch half: 0 or 1
    const int p     = strip * 256 + (int)threadIdx.x;
    const float* fbase = feat + (size_t)half * BH * Cn * HWn + p;

    float acc[TAPS][BH];
#pragma unroll
    for (int k = 0; k < TAPS; ++k)
#pragma unroll
        for (int b = 0; b < BH; ++b) acc[k][b] = 0.f;

    float buf[2][4][BH];                             // 32 VGPRs of stage regs

    // prologue: chunk 0 (c = 0..3)
#pragma unroll
    for (int ci = 0; ci < 4; ++ci)
#pragma unroll
        for (int b = 0; b < BH; ++b)
            buf[0][ci][b] = __builtin_nontemporal_load(
                fbase + (size_t)(b * Cn + ci) * HWn);

#pragma unroll
    for (int g = 0; g < 16; ++g) {
        const int cur = g & 1, nxt = cur ^ 1;
        if (g < 15) {                                // prefetch chunk g+1
            const int c0 = (g + 1) * 4;
#pragma unroll
            for (int ci = 0; ci < 4; ++ci)
#pragma unroll
                for (int b = 0; b < BH; ++b)
                    buf[nxt][ci][b] = __builtin_nontemporal_load(
                        fbase + (size_t)(b * Cn + c0 + ci) * HWn);
        }
#pragma unroll
        for (int ci = 0; ci < 4; ++ci) {
            const int c = g * 4 + ci;
#pragma unroll
            for (int k = 0; k < TAPS; ++k) {
                const float wv = wt[c * TAPS + k];   // uniform -> SGPR
#pragma unroll
                for (int b = 0; b < BH; ++b)
                    acc[k][b] = fmaf(buf[cur][ci][b], wv, acc[k][b]);
            }
        }
    }

    // store: one float4 per tap, lanes contiguous -> 1 KB/wave, fully coalesced
#pragma unroll
    for (int k = 0; k < TAPS; ++k) {
        float4* dst = (float4*)(D + ((size_t)(k * 2 + half) * HWn + p) * BH);
        *dst = make_float4(acc[k][0], acc[k][1], acc[k][2], acc[k][3]);
    }
}

// ---------------------------------------------------------------------------
// Pass 2: stage gi/gj via LDS (stride-9 reads conflict-free, gcd(9,32)=1),
// 18 coalesced float4 gathers from L2/L3-resident D (gi row-constant,
// gj = w+shift mod W -> consecutive lanes contiguous), sum taps,
// NT-write the 2x2-upsampled output.
// ---------------------------------------------------------------------------
__global__ __launch_bounds__(256) void pass2_gather(
    const float* __restrict__ D, const int* __restrict__ gi,
    const int* __restrict__ gj, float* __restrict__ out)
{
    __shared__ int loff[256 * TAPS];
    const int tid   = threadIdx.x;
    const int p0    = blockIdx.x * 256;
    const int gbase = p0 * TAPS;

#pragma unroll
    for (int i = tid; i < 256 * TAPS; i += 256)
        loff[i] = gi[gbase + i] * Wn + gj[gbase + i];
    __syncthreads();

    const int p = p0 + tid;
    const int w = p & (Wn - 1);
    const int h = p >> 9;

    int off[TAPS];
#pragma unroll
    for (int k = 0; k < TAPS; ++k) off[k] = loff[tid * TAPS + k];

    float4 x0[TAPS], x1[TAPS];                        // 18 gathers, all in flight
#pragma unroll
    for (int k = 0; k < TAPS; ++k) {
        x0[k] = *(const float4*)(D + ((size_t)(2 * k)     * HWn + off[k]) * BH);
        x1[k] = *(const float4*)(D + ((size_t)(2 * k + 1) * HWn + off[k]) * BH);
    }

    float a[Bn];
#pragma unroll
    for (int b = 0; b < Bn; ++b) a[b] = 0.f;
#pragma unroll
    for (int k = 0; k < TAPS; ++k) {
        a[0] += x0[k].x; a[1] += x0[k].y; a[2] += x0[k].z; a[3] += x0[k].w;
        a[4] += x1[k].x; a[5] += x1[k].y; a[6] += x1[k].z; a[7] += x1[k].w;
    }

#pragma unroll
    for (int b = 0; b < Bn; ++b) {
        vfloat2 vv = {a[b], a[b]};
        size_t o = ((size_t)b * (2 * Hn) + 2 * h) * (size_t)(2 * Wn) + 2 * w;
        __builtin_nontemporal_store(vv, (vfloat2*)(out + o));
        __builtin_nontemporal_store(vv, (vfloat2*)(out + o + 2 * Wn));
    }
}

// ---------------------------------------------------------------------------
// Fallback (ws too small): direct per-pixel 9x64 gather-dot.
// ---------------------------------------------------------------------------
__global__ __launch_bounds__(256) void direct_kernel(
    const float* __restrict__ feat, const float* __restrict__ wt,
    const int* __restrict__ gi, const int* __restrict__ gj,
    float* __restrict__ out)
{
    int p = blockIdx.x * blockDim.x + threadIdx.x;
    int w = p & (Wn - 1);
    int h = (p >> 9) & (Hn - 1);
    int b = p >> 17;

    int iidx = ((h << 9) | w) * TAPS;
    int off[TAPS];
#pragma unroll
    for (int k = 0; k < TAPS; ++k)
        off[k] = gi[iidx + k] * Wn + gj[iidx + k];

    float acc = 0.f;
    for (int c = 0; c < Cn; ++c) {
        const float* fc = feat + ((size_t)b * Cn + c) * HWn;
#pragma unroll
        for (int k = 0; k < TAPS; ++k)
            acc = fmaf(fc[off[k]], wt[c * TAPS + k], acc);
    }

    float2 v = make_float2(acc, acc);
    size_t o0 = ((size_t)b * (2 * Hn) + 2 * h) * (size_t)(2 * Wn) + 2 * w;
    *(float2*)(out + o0)          = v;
    *(float2*)(out + o0 + 2 * Wn) = v;
}

extern "C" void kernel_launch(void* const* d_in, const int* in_sizes, int n_in,
                              void* d_out, int out_size, void* d_ws, size_t ws_size,
                              hipStream_t stream) {
    const float* feat = (const float*)d_in[0];   // [8,64,256,512] fp32
    const float* wt   = (const float*)d_in[1];   // [1,64,3,3]     fp32
    const int*   gi   = (const int*)d_in[2];     // [256,512,9]    int32
    const int*   gj   = (const int*)d_in[3];     // [256,512,9]    int32
    float*       out  = (float*)d_out;           // [8,1,512,1024] fp32

    // D[k*2+half][p][b4]
    const size_t bytesD = (size_t)TAPS * 2 * HWn * BH * sizeof(float); // 37.75 MB

    if (ws_size >= bytesD) {
        float* D = (float*)d_ws;
        pass1_chandot<<<2 * (HWn / 256), 256, 0, stream>>>(feat, wt, D);
        pass2_gather <<<HWn / 256, 256, 0, stream>>>(D, gi, gj, out);
    } else {
        direct_kernel<<<(Bn * HWn) / 256, 256, 0, stream>>>(feat, wt, gi, gj, out);
    }
}